// Round 1
// baseline (516.080 us; speedup 1.0000x reference)
//
#include <hip/hip_runtime.h>

#define NA 32   // atoms A
#define NB 2    // batch B
#define NC 16   // channels C

// ---- coupling tables (l-grouped, reference loop order) ----
// l=0: (0,0,0),(1,1,0),(2,2,0)
// l=1: (0,1,1),(1,0,1),(1,1,1),(1,2,1),(2,1,1),(2,2,1)
// l=2: (0,2,2),(1,1,2),(1,2,2),(2,0,2),(2,1,2),(2,2,2)
constexpr int KL1[15]   = {0,1,2, 0,1,1,1,2,2, 0,1,1,2,2,2};
constexpr int KL2[15]   = {0,1,2, 1,0,1,2,1,2, 2,1,2,0,1,2};
constexpr int KOFF[15]  = {0,1,10, 35,44,53,80,125,170, 245,270,315,390,415,490};
constexpr int KLBASE[3] = {0,3,9};
constexpr int KLOFF[3]  = {0,1,4};
constexpr int KOFF3[3]  = {0,1024,4096};
__constant__ int CP_L1[15]   = {0,1,2, 0,1,1,1,2,2, 0,1,1,2,2,2};
__constant__ int CP_L2[15]   = {0,1,2, 1,0,1,2,1,2, 2,1,2,0,1,2};
__constant__ int CP_OFF[15]  = {0,1,10, 35,44,53,80,125,170, 245,270,315,390,415,490};
__constant__ int LBASE[3] = {0,3,9};
__constant__ int LOFF[3]  = {0,1,4};
__constant__ int OFF3[3]  = {0,1024,4096};

// ---------------- compile-time CG table ----------------
constexpr double cfact(int n){ double r=1.0; for(int i=2;i<=n;++i) r*=(double)i; return r; }
constexpr double csqrt(double x){
    double g = (x > 1.0) ? x : 1.0, prev = 0.0;
    for (int i = 0; i < 60 && g != prev; ++i) { prev = g; g = 0.5*(g + x/g); }
    return g;
}
struct CGT { float v[616]; };
constexpr CGT build_cg() {
    CGT t{};
    for (int cp=0; cp<15; ++cp){
        int l1=KL1[cp], l2=KL2[cp];
        int l = (cp<3)?0:((cp<9)?1:2);
        int n1=2*l1+1, n2=2*l2+1, nl=2*l+1;
        for (int x=0;x<n1;++x) for(int y=0;y<n2;++y) for(int z=0;z<nl;++z){
            int m1=x-l1, m2=y-l2, m=z-l;
            double val=0.0;
            if (m1+m2==m){
                double pre = csqrt((2.0*l+1.0)*cfact(l+l1-l2)*cfact(l-l1+l2)*cfact(l1+l2-l)/cfact(l1+l2+l+1));
                pre *= csqrt(cfact(l+m)*cfact(l-m)*cfact(l1+m1)*cfact(l1-m1)*cfact(l2+m2)*cfact(l2-m2));
                double s=0.0;
                for(int k=0;k<=l1+l2;++k){
                    int d0=k,d1=l1+l2-l-k,d2=l1-m1-k,d3=l2+m2-k,d4=l-l2+m1+k,d5=l-l1-m2+k;
                    if(d0<0||d1<0||d2<0||d3<0||d4<0||d5<0) continue;
                    double term = 1.0/(cfact(d0)*cfact(d1)*cfact(d2)*cfact(d3)*cfact(d4)*cfact(d5));
                    s += (k & 1) ? -term : term;
                }
                val = pre*s;
            }
            t.v[KOFF[cp] + (x*n2+y)*nl + z] = (float)val;
        }
    }
    return t;
}
__constant__ CGT CGC = build_cg();

// ---------------- K1: message pass + cg_nl + wnl mixing, one block per (l,b,z,i) ----------------
template<int L>
__device__ void nl_body(int i, int b, int z,
    const float* __restrict__ p0, const float* __restrict__ p1, const float* __restrict__ p2,
    const float* __restrict__ norms, const float* __restrict__ wnl,
    float* __restrict__ mnl, float* smem)
{
    constexpr int MD  = 2*L+1;
    constexpr int TAU = (L == 0) ? 768 : 1536;
    constexpr int NK  = TAU / 256;

    float* shCG = smem;            // 616
    float* mp   = smem + 616;      // 144 (this b only): [xt][c]
    float* shcg = mp + 144;        // TAU
    float* red  = shcg + TAU;      // 64 (16 float4)

    const int tid = threadIdx.x;
    const int wave = tid >> 6, lane = tid & 63;

    for (int e = tid; e < 616; e += 256) shCG[e] = CGC.v[e];

    // mp[xt][c] = sum_j conn(b,i,j) * parts[lp][b,j,x,c]   (predicated, unrolled)
    if (tid < 144) {
        int xt = tid >> 4, c = tid & 15;
        int lp = (xt < 1) ? 0 : ((xt < 4) ? 1 : 2);
        int x = xt - KLOFF[lp];
        int md = 2*lp+1;
        const float* pp = (lp == 0) ? p0 : ((lp == 1) ? p1 : p2);
        const float* nr = norms + (b*NA + i)*NA;
        float s = 0.0f;
#pragma unroll
        for (int j = 0; j < NA; ++j) {
            float msk = (nr[j] < 0.5f) ? 1.0f : 0.0f;
            s += msk * pp[((b*NA + j)*md + x)*NC + c];
        }
        mp[tid] = s;
    }
    __syncthreads();

    // stage b: shcg[t], t = k*256 + c*16 + d ; this thread: c = tid>>4, d = tid&15
    {
        const int c = tid >> 4, d = tid & 15;
#pragma unroll
        for (int k = 0; k < NK; ++k) {
            const int cp = KLBASE[L] + k;
            const int l1 = KL1[cp], l2 = KL2[cp];
            const int n1 = 2*l1+1, n2 = 2*l2+1;
            float s = 0.0f;
#pragma unroll
            for (int x = 0; x < n1; ++x) {
                float mv = mp[(KLOFF[l1] + x)*NC + c];
#pragma unroll
                for (int y = 0; y < n2; ++y)
                    s += shCG[KOFF[cp] + (x*n2 + y)*MD + z] * mv * mp[(KLOFF[l2] + y)*NC + d];
            }
            shcg[k*256 + tid] = s;
        }
    }
    __syncthreads();

    // stage c: out[c'] = sum_t shcg[t] * wnl[i,t,c']  — float4 loads, 4-wave t-split
    {
        constexpr int PER = TAU / 4;     // t-range per wave
        constexpr int IT  = PER / 16;
        const int t_low = lane >> 2, c4 = lane & 3;
        const float4* w4 = (const float4*)(wnl + (size_t)i * TAU * 16);
        float4 acc = make_float4(0.f, 0.f, 0.f, 0.f);
        const int tb = wave * PER + t_low;
#pragma unroll 4
        for (int it = 0; it < IT; ++it) {
            int t = tb + it * 16;
            float sc = shcg[t];
            float4 wv = w4[t * 4 + c4];
            acc.x += sc * wv.x; acc.y += sc * wv.y; acc.z += sc * wv.z; acc.w += sc * wv.w;
        }
#pragma unroll
        for (int m = 4; m <= 32; m <<= 1) {
            acc.x += __shfl_xor(acc.x, m); acc.y += __shfl_xor(acc.y, m);
            acc.z += __shfl_xor(acc.z, m); acc.w += __shfl_xor(acc.w, m);
        }
        float4* red4 = (float4*)red;
        if (lane < 4) red4[wave * 4 + lane] = acc;
    }
    __syncthreads();
    if (tid < 16) {
        const float4* red4 = (const float4*)red;
        int c4 = tid >> 2, comp = tid & 3;
        float s = 0.0f;
#pragma unroll
        for (int w = 0; w < 4; ++w) s += ((const float*)&red4[w * 4 + c4])[comp];
        mnl[KOFF3[L] + ((b*NA + i)*MD + z)*NC + tid] = s;
    }
}

// scalars body (used fused and standalone)
__device__ void scal_body(int b, int a, const float* __restrict__ pin,
                          float* __restrict__ out, float* sp)
{
    const int tid = threadIdx.x;
    for (int e = tid; e < 9*NC; e += 256) {
        int xt = e / NC, c = e % NC;
        int lp = (xt < 1) ? 0 : ((xt < 4) ? 1 : 2);
        sp[e] = pin[OFF3[lp] + ((b*NA + a)*(2*lp+1) + (xt - LOFF[lp]))*NC + c];
    }
    __syncthreads();
    float* orow = out + (size_t)(b*NA + a)*784;
    for (int e = tid; e < 784; e += 256) {
        float v;
        if (e < 16) {
            v = sp[e];
        } else {
            int g = e - 16;
            int lb = g >> 8; int c = (g >> 4) & 15; int d = g & 15;
            int md = 2*lb+1;
            float s = 0.0f;
            for (int zz = 0; zz < md; ++zz)
                s += sp[(LOFF[lb] + zz)*NC + c] * sp[(LOFF[lb] + zz)*NC + d];
            v = s;
        }
        orow[e] = v;
    }
}

// grid: 576 nl blocks (+64 scal blocks when prev_po != null, always launched)
__global__ __launch_bounds__(256) void k_nl(
    const float* __restrict__ p0, const float* __restrict__ p1, const float* __restrict__ p2,
    const float* __restrict__ norms,
    const float* __restrict__ w0, const float* __restrict__ w1, const float* __restrict__ w2,
    float* __restrict__ mnl, float* __restrict__ po,
    const float* __restrict__ prev_po, float* __restrict__ prev_out)
{
    __shared__ __align__(16) float smem[2360];
    const int bx = blockIdx.x;
    if (bx >= 576) {
        if (prev_po) {
            int sidx = bx - 576;
            scal_body(sidx >> 5, sidx & 31, prev_po, prev_out, smem);
        }
        return;
    }
    if (threadIdx.x < 16) po[bx*16 + threadIdx.x] = 0.0f;

    const int lq = bx >> 5, i = bx & 31;
    if (lq < 2)      nl_body<0>(i, lq, 0, p0, p1, p2, norms, w0, mnl, smem);
    else if (lq < 8) { int g = lq - 2; nl_body<1>(i, g/3, g%3, p0, p1, p2, norms, w1, mnl, smem); }
    else             { int g = lq - 8; nl_body<2>(i, g/5, g%5, p0, p1, p2, norms, w2, mnl, smem); }
}

// ---------------- K_wred: d-reduce wrel weights (sph channels are broadcast) ----------------
// wrel[l] layout: [i][j][t][16] with t = R*16 + d, R = (k,c)-row.  cg_rel is d-independent,
// so only w'[i][j][R][c'] = sum_d wrel[i][j][R*16+d][c'] ever enters the output.
// Segments per layer: l0 = 32*32*48 = 49152 rows (768 blocks), l1/l2 = 98304 rows (1536 blocks each).
// Grid = 3840 blocks, 64 rows/block, thread = (row, c4): 16 float4 loads (64B apart), 1 store.
__global__ __launch_bounds__(256) void k_wred(
    const float* __restrict__ s0, const float* __restrict__ s1, const float* __restrict__ s2,
    float* __restrict__ dst)
{
    const int b = blockIdx.x, tid = threadIdx.x;
    const float* src; size_t lrow, obase;
    if (b < 768)       { src = s0; lrow = (size_t)b*64;        obase = 0u;        }
    else if (b < 2304) { src = s1; lrow = (size_t)(b-768)*64;  obase = 786432u;   }
    else               { src = s2; lrow = (size_t)(b-2304)*64; obase = 2359296u;  }
    const size_t row = lrow + (size_t)(tid >> 2);
    const int c4 = tid & 3;
    const float4* sp = (const float4*)(src + row*256) + c4;
    float4 a = sp[0];
#pragma unroll
    for (int d = 1; d < 16; ++d) {
        float4 v = sp[(size_t)d*4];
        a.x += v.x; a.y += v.y; a.z += v.z; a.w += v.w;
    }
    ((float4*)(dst + obase + row*16))[c4] = a;
}

// ---------------- K2 (fast): rel CG product on d-reduced weights ----------------
// block = (L, i, jq); per block: 4 j's, NR rows, 16 c'.  Wave task = (jj, rb): 1KB coalesced
// float4 load; lane = (rloc, c4); per-lane G row; shfl over lane bits 2..5 sums the 16 R's.
template<int L>
__device__ void rel_body2(int i, int jq,
    const float* __restrict__ wr, const float* __restrict__ mnl,
    const float* __restrict__ relpos, float* __restrict__ pout,
    float* smem)
{
    constexpr int MD  = 2*L+1;
    constexpr int NBZ = 2*MD;                 // (b,z) pairs: 2,6,10
    constexpr int NR  = (L==0) ? 48 : 96;     // reduced (k,c)-rows per (i,j)
    constexpr int RB  = NR/16;                // row-blocks per j: 3 or 6

    float*  shCG = smem;                      // 616
    float*  shY  = shCG + 616;                // 72
    float*  shM  = shY + 72;                  // 288
    float*  shG  = shM + 288;                 // 4*NR*NBZ (max 3840)
    float4* shR  = (float4*)(shG + 4*NR*NBZ); // 16*NBZ float4

    const int tid = threadIdx.x;
    const int wave = tid >> 6, lane = tid & 63;

    for (int e = tid; e < 616; e += 256) shCG[e] = CGC.v[e];

    if (tid < 8) {
        int jj = tid >> 1, b = tid & 1;
        int j = (jq << 2) + jj;
        const float* rp = relpos + (((size_t)(b*NA + i))*NA + j)*3;
        float px = rp[0], py = rp[1], pz = rp[2];
        float rr = sqrtf(px*px + py*py + pz*pz + 1e-6f);
        float ux = px/rr, uy = py/rr, uz = pz/rr;
        float* Y = shY + tid*9;
        Y[0] = 0.28209479f;
        Y[1] = 0.48860251f*uy; Y[2] = 0.48860251f*uz; Y[3] = 0.48860251f*ux;
        Y[4] = 1.09254843f*ux*uy; Y[5] = 1.09254843f*uy*uz;
        Y[6] = 0.31539157f*(3.0f*uz*uz - 1.0f);
        Y[7] = 1.09254843f*ux*uz; Y[8] = 0.54627422f*(ux*ux - uy*uy);
    }
    for (int e = tid; e < NB*9*NC; e += 256) {
        int b = e / (9*NC); int rem = e % (9*NC);
        int xt = rem / NC;  int c = rem % NC;
        int lp = (xt < 1) ? 0 : ((xt < 4) ? 1 : 2);
        shM[e] = mnl[OFF3[lp] + ((b*NA + i)*(2*lp+1) + (xt - LOFF[lp]))*NC + c];
    }
    __syncthreads();

    // G[jj][R][q], q = b*MD+z
    for (int e = tid; e < 4*NR*NBZ; e += 256) {
        int q = e % NBZ; int R = (e/NBZ) % NR; int jj = e / (NBZ*NR);
        int b = q / MD, z = q % MD;
        int k = R >> 4, c = R & 15;
        int cp = LBASE[L] + k;
        int l1 = CP_L1[cp], l2 = CP_L2[cp];
        int n1 = 2*l1+1, n2 = 2*l2+1;
        const float* cgp = shCG + CP_OFF[cp];
        float s = 0.0f;
        for (int x = 0; x < n1; ++x) {
            float mv = shM[(b*9 + LOFF[l1] + x)*NC + c];
            for (int y = 0; y < n2; ++y)
                s += cgp[(x*n2 + y)*MD + z] * mv * shY[((jj<<1)+b)*9 + LOFF[l2] + y];
        }
        shG[e] = s;
    }
    __syncthreads();

    // stream reduced weights: task T = tt*4 + wave -> (jj = T/RB, rb = T%RB); 1KB/wave/task
    const float* wbase = wr + (size_t)(i*NA + (jq<<2)) * NR * 16;
    const int rloc = lane >> 2;
    float4 acc[NBZ];
#pragma unroll
    for (int q = 0; q < NBZ; ++q) acc[q] = make_float4(0.f,0.f,0.f,0.f);

#pragma unroll
    for (int tt = 0; tt < RB; ++tt) {
        const int T = tt*4 + wave;
        const int jj = T / RB, rb = T % RB;
        const float4 wv = ((const float4*)(wbase + ((size_t)(jj*NR) + rb*16)*16))[lane];
        const float* gp = shG + ((size_t)(jj*NR) + rb*16 + rloc)*NBZ;
        float g[NBZ];
#pragma unroll
        for (int q = 0; q < NBZ; ++q) g[q] = gp[q];
#pragma unroll
        for (int q = 0; q < NBZ; ++q) {
            acc[q].x += g[q]*wv.x; acc[q].y += g[q]*wv.y;
            acc[q].z += g[q]*wv.z; acc[q].w += g[q]*wv.w;
        }
    }

    // reduce over R (lanes xor 4..32), then across waves via LDS
#pragma unroll
    for (int q = 0; q < NBZ; ++q) {
        float4 v = acc[q];
#pragma unroll
        for (int m = 4; m <= 32; m <<= 1) {
            v.x += __shfl_xor(v.x, m); v.y += __shfl_xor(v.y, m);
            v.z += __shfl_xor(v.z, m); v.w += __shfl_xor(v.w, m);
        }
        acc[q] = v;
    }
    if (lane < 4) {
#pragma unroll
        for (int q = 0; q < NBZ; ++q) shR[(wave*4 + lane)*NBZ + q] = acc[q];
    }
    __syncthreads();
    for (int e = tid; e < NBZ*16; e += 256) {
        int q = e >> 4, cp = e & 15, qq = cp >> 2, cc = cp & 3;
        float s = 0.0f;
        for (int w = 0; w < 4; ++w) {
            const float* pr = (const float*)&shR[(w*4 + qq)*NBZ + q];
            s += pr[cc];
        }
        int b = q / MD, z = q % MD;
        atomicAdd(&pout[OFF3[L] + ((b*NA + i)*MD + z)*NC + cp], s);
    }
}

__global__ __launch_bounds__(256) void k_rel2(
    const float* __restrict__ mnl, const float* __restrict__ relpos,
    const float* __restrict__ w0, const float* __restrict__ w1, const float* __restrict__ w2,
    float* __restrict__ pout)
{
    __shared__ __align__(16) float smem[5456];
    const int bx = blockIdx.x;
    const int s = bx >> 8, idx = bx & 255;
    const int i = idx >> 3, jq = idx & 7;
    if (s == 0)      rel_body2<0>(i, jq, w0, mnl, relpos, pout, smem);
    else if (s == 1) rel_body2<1>(i, jq, w1, mnl, relpos, pout, smem);
    else             rel_body2<2>(i, jq, w2, mnl, relpos, pout, smem);
}

// ---------------- K2 (fallback): original full-stream version, used if ws too small ----------------
template<int L>
__device__ void rel_body_full(int i, int jq, int half,
    const float* __restrict__ wr, const float* __restrict__ mnl,
    const float* __restrict__ relpos, float* __restrict__ pout,
    float* smem)
{
    constexpr int MD  = 2*L+1;
    constexpr int NBZ = 2*MD;
    constexpr int TAU = (L==0) ? 768 : 1536;
    constexpr int P   = (L==2) ? 5 : 8;

    float*  shCG = smem;               // 616
    float*  shY  = smem + 616;         // 72
    float*  shM  = shY + 72;           // 288
    float*  shG  = shM + 288;          // 4*48*NBZ
    float4* shR  = (float4*)(shG + 4*48*NBZ); // 16*NBZ float4

    const int tid = threadIdx.x;
    const int wave = tid >> 6, lane = tid & 63;

    for (int e = tid; e < 616; e += 256) shCG[e] = CGC.v[e];

    if (tid < 8) {
        int jj = tid >> 1, b = tid & 1;
        int j = (jq << 2) + jj;
        const float* rp = relpos + (((size_t)(b*NA + i))*NA + j)*3;
        float px = rp[0], py = rp[1], pz = rp[2];
        float rr = sqrtf(px*px + py*py + pz*pz + 1e-6f);
        float ux = px/rr, uy = py/rr, uz = pz/rr;
        float* Y = shY + tid*9;
        Y[0] = 0.28209479f;
        Y[1] = 0.48860251f*uy; Y[2] = 0.48860251f*uz; Y[3] = 0.48860251f*ux;
        Y[4] = 1.09254843f*ux*uy; Y[5] = 1.09254843f*uy*uz;
        Y[6] = 0.31539157f*(3.0f*uz*uz - 1.0f);
        Y[7] = 1.09254843f*ux*uz; Y[8] = 0.54627422f*(ux*ux - uy*uy);
    }
    for (int e = tid; e < NB*9*NC; e += 256) {
        int b = e / (9*NC); int rem = e % (9*NC);
        int xt = rem / NC;  int c = rem % NC;
        int lp = (xt < 1) ? 0 : ((xt < 4) ? 1 : 2);
        shM[e] = mnl[OFF3[lp] + ((b*NA + i)*(2*lp+1) + (xt - LOFF[lp]))*NC + c];
    }
    __syncthreads();

    for (int e = tid; e < 4*48*NBZ; e += 256) {
        int q = e % NBZ; int r = (e/NBZ) % 48; int jj = e / (NBZ*48);
        int b = q / MD, z = q % MD;
        int R = half*48 + r; int k = R >> 4, c = R & 15;
        int cp = LBASE[L] + k;
        int l1 = CP_L1[cp], l2 = CP_L2[cp];
        int n1 = 2*l1+1, n2 = 2*l2+1;
        const float* cgp = shCG + CP_OFF[cp];
        float s = 0.0f;
        for (int x = 0; x < n1; ++x) {
            float mv = shM[(b*9 + LOFF[l1] + x)*NC + c];
            for (int y = 0; y < n2; ++y)
                s += cgp[(x*n2 + y)*MD + z] * mv * shY[((jj<<1)+b)*9 + LOFF[l2] + y];
        }
        shG[e] = s;
    }
    __syncthreads();

    const float* wbase = wr + ((size_t)(i*NA + (jq<<2))*TAU + half*(TAU/2))*16;
    const float* tb = wbase + tid*4;

    float4 buf[P];
#pragma unroll
    for (int c = 0; c < P; ++c)
        buf[c] = *(const float4*)(tb + (size_t)(c/12)*TAU*16 + (c%12)*1024);

    float4 acc[NBZ];
#pragma unroll
    for (int q = 0; q < NBZ; ++q) acc[q] = make_float4(0.f,0.f,0.f,0.f);

#pragma unroll
    for (int c = 0; c < 48; ++c) {
        const float4 v = buf[c % P];
        if (c + P < 48)
            buf[c % P] = *(const float4*)(tb + (size_t)((c+P)/12)*TAU*16 + ((c+P)%12)*1024);
        const int jj = c/12, r = (c%12)*4 + wave;
        const float* gp = shG + (jj*48 + r)*NBZ;
        float g[NBZ];
#pragma unroll
        for (int q = 0; q < NBZ; ++q) g[q] = gp[q];
#pragma unroll
        for (int q = 0; q < NBZ; ++q) {
            acc[q].x += g[q]*v.x; acc[q].y += g[q]*v.y;
            acc[q].z += g[q]*v.z; acc[q].w += g[q]*v.w;
        }
    }

#pragma unroll
    for (int q = 0; q < NBZ; ++q) {
        float4 v = acc[q];
#pragma unroll
        for (int m = 4; m <= 32; m <<= 1) {
            v.x += __shfl_xor(v.x, m); v.y += __shfl_xor(v.y, m);
            v.z += __shfl_xor(v.z, m); v.w += __shfl_xor(v.w, m);
        }
        acc[q] = v;
    }
    if (lane < 4) {
#pragma unroll
        for (int q = 0; q < NBZ; ++q) shR[(wave*4 + lane)*NBZ + q] = acc[q];
    }
    __syncthreads();
    for (int e = tid; e < NBZ*16; e += 256) {
        int q = e >> 4, cp = e & 15, qq = cp >> 2, cc = cp & 3;
        float s = 0.0f;
        for (int w = 0; w < 4; ++w) {
            const float* pr = (const float*)&shR[(w*4 + qq)*NBZ + q];
            s += pr[cc];
        }
        int b = q / MD, z = q % MD;
        atomicAdd(&pout[OFF3[L] + ((b*NA + i)*MD + z)*NC + cp], s);
    }
}

__global__ __launch_bounds__(256, 5) void k_rel_full(
    const float* __restrict__ mnl, const float* __restrict__ relpos,
    const float* __restrict__ wr0, const float* __restrict__ wr1, const float* __restrict__ wr2,
    float* __restrict__ pout)
{
    __shared__ __align__(16) float smem[3536];
    const int bx = blockIdx.x;
    const int s = bx >> 8, idx = bx & 255;
    const int i = idx >> 3, jq = idx & 7;
    if (s == 0)      rel_body_full<0>(i, jq, 0, wr0, mnl, relpos, pout, smem);
    else if (s == 1) rel_body_full<1>(i, jq, 0, wr1, mnl, relpos, pout, smem);
    else if (s == 2) rel_body_full<1>(i, jq, 1, wr1, mnl, relpos, pout, smem);
    else if (s == 3) rel_body_full<2>(i, jq, 0, wr2, mnl, relpos, pout, smem);
    else             rel_body_full<2>(i, jq, 1, wr2, mnl, relpos, pout, smem);
}

// ---------------- K3: standalone scalars (last layer) ----------------
__global__ __launch_bounds__(256) void k_scal(const float* __restrict__ pin, float* __restrict__ out)
{
    __shared__ float sp[9*NC];
    scal_body(blockIdx.x >> 5, blockIdx.x & 31, pin, out, sp);
}

// ---------------- host launch ----------------
extern "C" void kernel_launch(void* const* d_in, const int* in_sizes, int n_in,
                              void* d_out, int out_size, void* d_ws, size_t ws_size,
                              hipStream_t stream)
{
    const float* v0     = (const float*)d_in[0];
    const float* v1     = (const float*)d_in[1];
    const float* v2     = (const float*)d_in[2];
    const float* relpos = (const float*)d_in[3];
    const float* norms  = (const float*)d_in[4];
    const float* wnl[2][3] = {
        {(const float*)d_in[5],  (const float*)d_in[7],  (const float*)d_in[9]},
        {(const float*)d_in[11], (const float*)d_in[13], (const float*)d_in[15]}};
    const float* wrel[2][3] = {
        {(const float*)d_in[6],  (const float*)d_in[8],  (const float*)d_in[10]},
        {(const float*)d_in[12], (const float*)d_in[14], (const float*)d_in[16]}};

    float* ws  = (float*)d_ws;
    float* mnl = ws;            // 9216 floats
    float* pA  = ws + 9216;     // 9216 floats (layer-0 parts)
    float* pB  = ws + 18432;    // 9216 floats (layer-1 parts)
    float* wred = ws + 27648;   // 3932160 floats (per-layer d-reduced wrel, reused)
    float* out = (float*)d_out;

    const size_t WRED_FLOATS = 3932160;  // 786432 + 1572864 + 1572864
    const bool fast = ws_size >= (size_t)(27648 + WRED_FLOATS) * sizeof(float);

    if (fast) {
        // layer 0
        k_wred<<<3840, 256, 0, stream>>>(wrel[0][0], wrel[0][1], wrel[0][2], wred);
        k_nl<<<640, 256, 0, stream>>>(v0, v1, v2, norms,
                                      wnl[0][0], wnl[0][1], wnl[0][2], mnl, pA,
                                      nullptr, nullptr);
        k_rel2<<<768, 256, 0, stream>>>(mnl, relpos,
                                        wred, wred + 786432, wred + 2359296, pA);
        // layer 1 (+ fused scalars of layer 0)
        k_wred<<<3840, 256, 0, stream>>>(wrel[1][0], wrel[1][1], wrel[1][2], wred);
        k_nl<<<640, 256, 0, stream>>>(pA, pA + 1024, pA + 4096, norms,
                                      wnl[1][0], wnl[1][1], wnl[1][2], mnl, pB,
                                      pA, out);
        k_rel2<<<768, 256, 0, stream>>>(mnl, relpos,
                                        wred, wred + 786432, wred + 2359296, pB);
        k_scal<<<64, 256, 0, stream>>>(pB, out + (size_t)NB * NA * 784);
    } else {
        // fallback: original full-stream path
        k_nl<<<640, 256, 0, stream>>>(v0, v1, v2, norms,
                                      wnl[0][0], wnl[0][1], wnl[0][2], mnl, pA,
                                      nullptr, nullptr);
        k_rel_full<<<1280, 256, 0, stream>>>(mnl, relpos, wrel[0][0], wrel[0][1], wrel[0][2], pA);
        k_nl<<<640, 256, 0, stream>>>(pA, pA + 1024, pA + 4096, norms,
                                      wnl[1][0], wnl[1][1], wnl[1][2], mnl, pB,
                                      pA, out);
        k_rel_full<<<1280, 256, 0, stream>>>(mnl, relpos, wrel[1][0], wrel[1][1], wrel[1][2], pB);
        k_scal<<<64, 256, 0, stream>>>(pB, out + (size_t)NB * NA * 784);
    }
}